// Round 16
// baseline (132.192 us; speedup 1.0000x reference)
//
#include <hip/hip_runtime.h>
#include <stdint.h>

// VQ-VAE vector quantizer — fp32, NCHW input [64,64,32,32], emb [1024,64].
// r12/r15 configuration (launch_bounds(256,4), 64 pts/block, VGPR=64 clean)
// + LDS X-staging: the A-fragment build was 16k scalar 4KB-strided global
// loads per block (~65k L1 segments on the TA pipe — the hidden 60% stall).
// Now X is staged coalesced into LDS bf16 once, frags come from ds_read_b128.
// Math unchanged (absmax 0.0 ten rounds):
//   score = G - C/2 (MFMA acc-init) => argmin(dist) = argmax(score)
//   sweep1 -> smax; thr = smax - (2^-6*sqrt(A)*emax + 6e-5) [proven window]
//   sweep2 -> candidates via ballot + owner-lane LDS writes
//   rescue: tot==1 -> winner, else exact np-fp32 eval, overflow -> full scan
//   epilogue: quantized NCHW + per-block loss partial (plain store)
constexpr int KCODES = 1024;
constexpr int DDIM   = 64;
constexpr int HW     = 1024;
constexpr int NPTS   = 65536;
constexpr int PPB    = 64;            // points per block
constexpr int NBLK   = NPTS / PPB;    // 1024

constexpr int OUT_Q    = 0;
constexpr int OUT_IDX  = 4194304;
constexpr int OUT_LOSS = 4259840;
constexpr int OUT_NLL  = 4259841;

// ws 32-bit-unit offsets
constexpr int WS_MAXC  = 0;       // 4 f   : per-init-block max C
constexpr int WS_C     = 16;      // 1024 f: exact np C_k
constexpr int WS_E     = 2048;    // 32768 u32: bf16-E rows (1024 x 32)
constexpr int WS_PART  = 34816;   // 1024 f: per-block loss partials

typedef __attribute__((ext_vector_type(8))) short short8v;
typedef __attribute__((ext_vector_type(4))) float float4v;

__device__ __forceinline__ uint16_t f2bf(float f) {   // RNE fp32->bf16
    uint32_t u = __float_as_uint(f);
    return (uint16_t)((u + 0x7fffu + ((u >> 16) & 1u)) >> 16);
}
__device__ __forceinline__ uint32_t pack2bf(float a, float b) {
    return (uint32_t)f2bf(a) | ((uint32_t)f2bf(b) << 16);
}

__device__ __forceinline__ float np_pairwise_sumsq64(const float* a) {
    float r[8];
    #pragma unroll
    for (int j = 0; j < 8; ++j) r[j] = __fmul_rn(a[j], a[j]);
    #pragma unroll
    for (int i = 8; i < 64; i += 8)
        #pragma unroll
        for (int j = 0; j < 8; ++j)
            r[j] = __fadd_rn(r[j], __fmul_rn(a[i + j], a[i + j]));
    return __fadd_rn(__fadd_rn(__fadd_rn(r[0], r[1]), __fadd_rn(r[2], r[3])),
                     __fadd_rn(__fadd_rn(r[4], r[5]), __fadd_rn(r[6], r[7])));
}

// 4 blocks x 256 threads: code k = blockIdx*256 + tid
__global__ __launch_bounds__(256) void vq_init(const float* __restrict__ emb,
                                               float* __restrict__ ws) {
    __shared__ float smax[4];
    const int k = blockIdx.x * 256 + threadIdx.x;
    float row[DDIM];
    const float4* src = (const float4*)(emb + (size_t)k * DDIM);
    #pragma unroll
    for (int j = 0; j < 16; ++j) ((float4*)row)[j] = src[j];
    float C = np_pairwise_sumsq64(row);
    ws[WS_C + k] = C;
    uint32_t* eb = (uint32_t*)ws + WS_E + (size_t)k * 32;
    #pragma unroll
    for (int j = 0; j < 32; ++j)
        eb[j] = pack2bf(row[2 * j], row[2 * j + 1]);
    float m = C;
    #pragma unroll
    for (int off = 32; off > 0; off >>= 1) m = fmaxf(m, __shfl_down(m, off, 64));
    if ((threadIdx.x & 63) == 0) smax[threadIdx.x >> 6] = m;
    __syncthreads();
    if (threadIdx.x == 0)
        ws[WS_MAXC + blockIdx.x] =
            fmaxf(fmaxf(smax[0], smax[1]), fmaxf(smax[2], smax[3]));
}

constexpr int ROWB = 144;   // LDS X row bytes (128B data + 16B pad, 16B-aligned)

__global__ __launch_bounds__(256, 4) void vq_main(
        const float* __restrict__ inp, const float* __restrict__ emb,
        float* __restrict__ ws, float* __restrict__ out)
{
    __shared__ __align__(16) uint16_t sXb[PPB * (ROWB / 2)];  // 9216 B
    __shared__ float    sA[PPB];
    __shared__ float    sPart[4][PPB];
    __shared__ float    sThr[PPB];
    __shared__ uint16_t sCand[PPB * 4 * 8];
    __shared__ uint8_t  sCnt[PPB * 4];
    __shared__ int      sWin[PPB];
    __shared__ float    sred[4];

    const int tid  = threadIdx.x;
    const int lane = tid & 63;
    const int wave = tid >> 6;          // = code quarter
    const int col  = lane & 15;
    const int quad = lane >> 4;
    const int base = blockIdx.x * PPB;
    const int b    = base >> 10;
    const int hw0  = base & 1023;

    // ---- stage X to LDS bf16: fully coalesced (256B line per d-row) --------
    // thread t handles point p=lane, dims d0..d0+3 with d0 = 4*(i*4+wave)
    {
        const float* xb = inp + (size_t)b * DDIM * HW + hw0;
        #pragma unroll
        for (int i = 0; i < 4; ++i) {
            const int d0 = (i * 4 + wave) * 4;
            float v0 = xb[(size_t)(d0    ) * HW + lane];
            float v1 = xb[(size_t)(d0 + 1) * HW + lane];
            float v2 = xb[(size_t)(d0 + 2) * HW + lane];
            float v3 = xb[(size_t)(d0 + 3) * HW + lane];
            uint2 pk = { pack2bf(v0, v1), pack2bf(v2, v3) };
            *(uint2*)((char*)sXb + lane * ROWB + d0 * 2) = pk;
        }
    }

    // ---- prologue: exact A per point (wave 0, coalesced per d) -------------
    if (tid < PPB) {
        const float* xin = inp + (size_t)b * DDIM * HW + (hw0 + tid);
        float x[DDIM];
        #pragma unroll
        for (int d = 0; d < DDIM; ++d) x[d] = xin[(size_t)d * HW];
        sA[tid] = np_pairwise_sumsq64(x);
    }
    __syncthreads();

    // ---- A-fragments from LDS (8 x ds_read_b128 per thread) ----------------
    short8v a[4][2];
    #pragma unroll
    for (int g = 0; g < 4; ++g) {
        const char* xr = (const char*)sXb + (g * 16 + col) * ROWB + quad * 16;
        a[g][0] = *(const short8v*)(xr);
        a[g][1] = *(const short8v*)(xr + 64);
    }

    const uint16_t* Eb = (const uint16_t*)((const uint32_t*)ws + WS_E);
    const float*    Cw = ws + WS_C;
    const int k0 = wave * 256;

    // ---- sweep 1: per-point score-max, depth-2 pipelined loads -------------
    float smaxv[4][4];
    #pragma unroll
    for (int g = 0; g < 4; ++g)
        #pragma unroll
        for (int r = 0; r < 4; ++r) smaxv[g][r] = -3.0e38f;

    {
        const uint16_t* e0 = Eb + (size_t)(k0 + col) * DDIM + quad * 8;
        const uint16_t* e1 = Eb + (size_t)(k0 + 16 + col) * DDIM + quad * 8;
        short8v pa0 = *(const short8v*)(e0), pa1 = *(const short8v*)(e0 + 32);
        short8v pb0 = *(const short8v*)(e1), pb1 = *(const short8v*)(e1 + 32);
        float   cia = Cw[k0 + col] * -0.5f;
        float   cib = Cw[k0 + 16 + col] * -0.5f;
        #pragma unroll 1
        for (int c2 = 0; c2 < 16; c2 += 2) {
            short8v u0 = pa0, u1 = pa1; float uci = cia;
            if (c2 + 2 < 16) {
                const uint16_t* er = Eb + (size_t)(k0 + (c2 + 2) * 16 + col) * DDIM + quad * 8;
                pa0 = *(const short8v*)(er);
                pa1 = *(const short8v*)(er + 32);
                cia = Cw[k0 + (c2 + 2) * 16 + col] * -0.5f;
            }
            float4v ci4 = {uci, uci, uci, uci};
            #pragma unroll
            for (int g = 0; g < 4; ++g) {
                float4v acc = ci4;
                acc = __builtin_amdgcn_mfma_f32_16x16x32_bf16(a[g][0], u0, acc, 0, 0, 0);
                acc = __builtin_amdgcn_mfma_f32_16x16x32_bf16(a[g][1], u1, acc, 0, 0, 0);
                #pragma unroll
                for (int r = 0; r < 4; ++r) smaxv[g][r] = fmaxf(smaxv[g][r], acc[r]);
            }
            short8v v0 = pb0, v1 = pb1; float vci = cib;
            if (c2 + 3 < 16) {
                const uint16_t* er = Eb + (size_t)(k0 + (c2 + 3) * 16 + col) * DDIM + quad * 8;
                pb0 = *(const short8v*)(er);
                pb1 = *(const short8v*)(er + 32);
                cib = Cw[k0 + (c2 + 3) * 16 + col] * -0.5f;
            }
            float4v ci4b = {vci, vci, vci, vci};
            #pragma unroll
            for (int g = 0; g < 4; ++g) {
                float4v acc = ci4b;
                acc = __builtin_amdgcn_mfma_f32_16x16x32_bf16(a[g][0], v0, acc, 0, 0, 0);
                acc = __builtin_amdgcn_mfma_f32_16x16x32_bf16(a[g][1], v1, acc, 0, 0, 0);
                #pragma unroll
                for (int r = 0; r < 4; ++r) smaxv[g][r] = fmaxf(smaxv[g][r], acc[r]);
            }
        }
    }
    #pragma unroll
    for (int g = 0; g < 4; ++g)
        #pragma unroll
        for (int r = 0; r < 4; ++r) {
            float m = smaxv[g][r];
            m = fmaxf(m, __shfl_xor(m, 1, 16));
            m = fmaxf(m, __shfl_xor(m, 2, 16));
            m = fmaxf(m, __shfl_xor(m, 4, 16));
            m = fmaxf(m, __shfl_xor(m, 8, 16));
            if (col == 0) sPart[wave][g * 16 + quad * 4 + r] = m;
        }
    __syncthreads();

    // ---- per-point threshold ------------------------------------------------
    if (tid < PPB) {
        float gm = fmaxf(fmaxf(sPart[0][tid], sPart[1][tid]),
                         fmaxf(sPart[2][tid], sPart[3][tid]));
        float mc = fmaxf(fmaxf(ws[WS_MAXC], ws[WS_MAXC + 1]),
                         fmaxf(ws[WS_MAXC + 2], ws[WS_MAXC + 3]));
        sThr[tid] = gm - (0.015625f * sqrtf(sA[tid]) * sqrtf(mc) + 6e-5f);
    }
    __syncthreads();

    float thr[4][4];
    #pragma unroll
    for (int g = 0; g < 4; ++g)
        #pragma unroll
        for (int r = 0; r < 4; ++r) thr[g][r] = sThr[g * 16 + quad * 4 + r];

    // ---- sweep 2: candidates (identical MFMA, depth-2 pipeline, ballot) ----
    int cnt[4][4];
    #pragma unroll
    for (int g = 0; g < 4; ++g)
        #pragma unroll
        for (int r = 0; r < 4; ++r) cnt[g][r] = 0;

    {
        const uint16_t* e0 = Eb + (size_t)(k0 + col) * DDIM + quad * 8;
        const uint16_t* e1 = Eb + (size_t)(k0 + 16 + col) * DDIM + quad * 8;
        short8v pa0 = *(const short8v*)(e0), pa1 = *(const short8v*)(e0 + 32);
        short8v pb0 = *(const short8v*)(e1), pb1 = *(const short8v*)(e1 + 32);
        float   cia = Cw[k0 + col] * -0.5f;
        float   cib = Cw[k0 + 16 + col] * -0.5f;
        #pragma unroll 1
        for (int c2 = 0; c2 < 16; c2 += 2) {
            short8v u0 = pa0, u1 = pa1; float uci = cia;
            if (c2 + 2 < 16) {
                const uint16_t* er = Eb + (size_t)(k0 + (c2 + 2) * 16 + col) * DDIM + quad * 8;
                pa0 = *(const short8v*)(er);
                pa1 = *(const short8v*)(er + 32);
                cia = Cw[k0 + (c2 + 2) * 16 + col] * -0.5f;
            }
            float4v ci4 = {uci, uci, uci, uci};
            #pragma unroll
            for (int g = 0; g < 4; ++g) {
                float4v acc = ci4;
                acc = __builtin_amdgcn_mfma_f32_16x16x32_bf16(a[g][0], u0, acc, 0, 0, 0);
                acc = __builtin_amdgcn_mfma_f32_16x16x32_bf16(a[g][1], u1, acc, 0, 0, 0);
                #pragma unroll
                for (int r = 0; r < 4; ++r) {
                    unsigned long long bm = __ballot(acc[r] >= thr[g][r]);
                    if (col == 0) {
                        unsigned gm = (unsigned)(bm >> (quad * 16)) & 0xffffu;
                        while (gm) {
                            int bit = __ffs(gm) - 1;
                            gm &= gm - 1;
                            int ct = cnt[g][r];
                            if (ct < 8)
                                sCand[((g * 16 + quad * 4 + r) * 4 + wave) * 8 + ct] =
                                    (uint16_t)(k0 + c2 * 16 + bit);
                            cnt[g][r] = ct + 1;
                        }
                    }
                }
            }
            short8v v0 = pb0, v1 = pb1; float vci = cib;
            if (c2 + 3 < 16) {
                const uint16_t* er = Eb + (size_t)(k0 + (c2 + 3) * 16 + col) * DDIM + quad * 8;
                pb0 = *(const short8v*)(er);
                pb1 = *(const short8v*)(er + 32);
                cib = Cw[k0 + (c2 + 3) * 16 + col] * -0.5f;
            }
            float4v ci4b = {vci, vci, vci, vci};
            #pragma unroll
            for (int g = 0; g < 4; ++g) {
                float4v acc = ci4b;
                acc = __builtin_amdgcn_mfma_f32_16x16x32_bf16(a[g][0], v0, acc, 0, 0, 0);
                acc = __builtin_amdgcn_mfma_f32_16x16x32_bf16(a[g][1], v1, acc, 0, 0, 0);
                #pragma unroll
                for (int r = 0; r < 4; ++r) {
                    unsigned long long bm = __ballot(acc[r] >= thr[g][r]);
                    if (col == 0) {
                        unsigned gm = (unsigned)(bm >> (quad * 16)) & 0xffffu;
                        while (gm) {
                            int bit = __ffs(gm) - 1;
                            gm &= gm - 1;
                            int ct = cnt[g][r];
                            if (ct < 8)
                                sCand[((g * 16 + quad * 4 + r) * 4 + wave) * 8 + ct] =
                                    (uint16_t)(k0 + (c2 + 1) * 16 + bit);
                            cnt[g][r] = ct + 1;
                        }
                    }
                }
            }
        }
    }
    if (col == 0) {
        #pragma unroll
        for (int g = 0; g < 4; ++g)
            #pragma unroll
            for (int r = 0; r < 4; ++r) {
                int c = cnt[g][r];
                sCnt[(g * 16 + quad * 4 + r) * 4 + wave] = (uint8_t)(c > 255 ? 255 : c);
            }
    }
    __syncthreads();

    // ---- rescue: exact np-fp32 on candidates -------------------------------
    if (tid < PPB) {
        const int p = tid, n = base + p;
        int cq[4], tot = 0, cmax = 0;
        #pragma unroll
        for (int q = 0; q < 4; ++q) {
            cq[q] = sCnt[p * 4 + q];
            tot += cq[q];
            cmax = cq[q] > cmax ? cq[q] : cmax;
        }
        int win;
        if (tot == 1) {
            win = 0;
            #pragma unroll
            for (int q = 0; q < 4; ++q)
                if (cq[q]) win = sCand[(p * 4 + q) * 8];
        } else {
            const float* xin = inp + (size_t)b * DDIM * HW + (hw0 + p);
            float x[DDIM];
            #pragma unroll
            for (int d = 0; d < DDIM; ++d) x[d] = xin[(size_t)d * HW];
            const float A = sA[p];
            float bd = 3.0e38f; win = KCODES - 1;
            if (cmax <= 8) {
                #pragma unroll 1
                for (int q = 0; q < 4; ++q) {
                    #pragma unroll 1
                    for (int i = 0; i < cq[q]; ++i) {   // ascending k order
                        int k = sCand[(p * 4 + q) * 8 + i];
                        float e[DDIM];
                        const float4* e4 = (const float4*)(emb + (size_t)k * DDIM);
                        #pragma unroll
                        for (int j = 0; j < 16; ++j) ((float4*)e)[j] = e4[j];
                        float g = 0.f;
                        #pragma unroll
                        for (int d = 0; d < DDIM; ++d) g = fmaf(x[d], e[d], g);
                        float dd = __fadd_rn(__fsub_rn(A, __fmul_rn(2.0f, g)), Cw[k]);
                        if (dd < bd || (dd == bd && k < win)) { bd = dd; win = k; }
                    }
                }
            } else {                                    // overflow safety
                #pragma unroll 1
                for (int k = 0; k < KCODES; ++k) {
                    float e[DDIM];
                    const float4* e4 = (const float4*)(emb + (size_t)k * DDIM);
                    #pragma unroll
                    for (int j = 0; j < 16; ++j) ((float4*)e)[j] = e4[j];
                    float g = 0.f;
                    #pragma unroll
                    for (int d = 0; d < DDIM; ++d) g = fmaf(x[d], e[d], g);
                    float dd = __fadd_rn(__fsub_rn(A, __fmul_rn(2.0f, g)), Cw[k]);
                    if (dd < bd) { bd = dd; win = k; }
                }
            }
        }
        sWin[p] = win;
        out[OUT_IDX + n] = (float)win;
    }
    __syncthreads();

    // ---- epilogue: quantized NCHW + loss partial (plain store) -------------
    {
        const int pl = tid & 63, qtr = tid >> 6;
        const int win = sWin[pl];
        const int ch0 = qtr * 16;
        float q[16];
        const float4* q4 = (const float4*)(emb + (size_t)win * DDIM + ch0);
        #pragma unroll
        for (int j = 0; j < 4; ++j) ((float4*)q)[j] = q4[j];
        const size_t off = (size_t)b * DDIM * HW + (size_t)ch0 * HW + (hw0 + pl);
        const float* xin2 = inp + off;
        float* orow = out + off;
        float lacc = 0.f;
        #pragma unroll
        for (int j = 0; j < 16; ++j) {
            float xv = xin2[(size_t)j * HW];
            float diff = __fsub_rn(q[j], xv);
            orow[(size_t)j * HW] = __fadd_rn(xv, diff);   // ref's x + (q - x)
            lacc = fmaf(diff, diff, lacc);
        }
        #pragma unroll
        for (int o2 = 32; o2 > 0; o2 >>= 1) lacc += __shfl_down(lacc, o2, 64);
        if (lane == 0) sred[wave] = lacc;
    }
    __syncthreads();
    if (tid == 0)
        ws[WS_PART + blockIdx.x] = sred[0] + sred[1] + sred[2] + sred[3];
}

// 1 block x 256: reduce 1024 partials -> loss; write nll
__global__ __launch_bounds__(256) void vq_fin(const float* __restrict__ ws,
                                              float* __restrict__ out) {
    __shared__ float sred[4];
    const int tid = threadIdx.x;
    float s = 0.f;
    #pragma unroll
    for (int j = 0; j < 4; ++j) s += ws[WS_PART + j * 256 + tid];
    #pragma unroll
    for (int off = 32; off > 0; off >>= 1) s += __shfl_down(s, off, 64);
    if ((tid & 63) == 0) sred[tid >> 6] = s;
    __syncthreads();
    if (tid == 0) {
        float L = sred[0] + sred[1] + sred[2] + sred[3];
        out[OUT_LOSS] = L * (1.25f / 4194304.0f);   // (1+CC)*mean over N*D
        out[OUT_NLL]  = 1.0f;
    }
}

extern "C" void kernel_launch(void* const* d_in, const int* in_sizes, int n_in,
                              void* d_out, int out_size, void* d_ws, size_t ws_size,
                              hipStream_t stream) {
    const float* inp = (const float*)d_in[0];
    const float* emb = (const float*)d_in[1];
    float* out = (float*)d_out;
    float* ws  = (float*)d_ws;

    vq_init<<<4, 256, 0, stream>>>(emb, ws);
    vq_main<<<NBLK, 256, 0, stream>>>(inp, emb, ws, out);
    vq_fin<<<1, 256, 0, stream>>>(ws, out);
}

// Round 17
// 119.240 us; speedup vs baseline: 1.1086x; 1.1086x over previous
//
#include <hip/hip_runtime.h>
#include <stdint.h>

// VQ-VAE vector quantizer — fp32, NCHW input [64,64,32,32], emb [1024,64].
// r15 kernel (launch_bounds(256,4), 64 pts/block, VGPR=64, absmax 0.0) with
// ONE change: the bf16-E table is pre-SWIZZLED into exact MFMA B-fragment
// order, so each sweep load is a single contiguous 1KB wave transaction
// (was: 64x16B gather over 16 scattered 128B rows -> 16-32 segments/instr).
// Layout: chunk c (16 codes) occupies 2KB: [0,1K) = b0 plane, [1K,2K) = b1;
// lane l=(quad*16+col) reads its 16B at c*2048 + plane*1024 + l*16.
constexpr int KCODES = 1024;
constexpr int DDIM   = 64;
constexpr int HW     = 1024;
constexpr int NPTS   = 65536;
constexpr int PPB    = 64;            // points per block
constexpr int NBLK   = NPTS / PPB;    // 1024

constexpr int OUT_Q    = 0;
constexpr int OUT_IDX  = 4194304;
constexpr int OUT_LOSS = 4259840;
constexpr int OUT_NLL  = 4259841;

// ws 32-bit-unit offsets
constexpr int WS_MAXC  = 0;       // 4 f   : per-init-block max C
constexpr int WS_C     = 16;      // 1024 f: exact np C_k
constexpr int WS_E     = 2048;    // 32768 u32: SWIZZLED bf16-E (64 chunks x 2KB)
constexpr int WS_PART  = 34816;   // 1024 f: per-block loss partials

typedef __attribute__((ext_vector_type(8))) short short8v;
typedef __attribute__((ext_vector_type(4))) float float4v;

__device__ __forceinline__ uint16_t f2bf(float f) {   // RNE fp32->bf16
    uint32_t u = __float_as_uint(f);
    return (uint16_t)((u + 0x7fffu + ((u >> 16) & 1u)) >> 16);
}
__device__ __forceinline__ uint32_t pack2bf(float a, float b) {
    return (uint32_t)f2bf(a) | ((uint32_t)f2bf(b) << 16);
}

__device__ __forceinline__ float np_pairwise_sumsq64(const float* a) {
    float r[8];
    #pragma unroll
    for (int j = 0; j < 8; ++j) r[j] = __fmul_rn(a[j], a[j]);
    #pragma unroll
    for (int i = 8; i < 64; i += 8)
        #pragma unroll
        for (int j = 0; j < 8; ++j)
            r[j] = __fadd_rn(r[j], __fmul_rn(a[i + j], a[i + j]));
    return __fadd_rn(__fadd_rn(__fadd_rn(r[0], r[1]), __fadd_rn(r[2], r[3])),
                     __fadd_rn(__fadd_rn(r[4], r[5]), __fadd_rn(r[6], r[7])));
}

// 4 blocks x 256 threads: code k = blockIdx*256 + tid. Writes SWIZZLED E.
__global__ __launch_bounds__(256) void vq_init(const float* __restrict__ emb,
                                               float* __restrict__ ws) {
    __shared__ float smax[4];
    const int k = blockIdx.x * 256 + threadIdx.x;
    float row[DDIM];
    const float4* src = (const float4*)(emb + (size_t)k * DDIM);
    #pragma unroll
    for (int j = 0; j < 16; ++j) ((float4*)row)[j] = src[j];
    float C = np_pairwise_sumsq64(row);
    ws[WS_C + k] = C;
    // swizzled write: chunk c=k>>4, col=k&15; for quad q: 16B piece
    {
        const int c = k >> 4, col = k & 15;
        uint32_t* eb = (uint32_t*)ws + WS_E + c * 512;   // chunk base (u32)
        #pragma unroll
        for (int q = 0; q < 4; ++q) {
            uint32_t* d0 = eb + (q * 16 + col) * 4;          // b0 plane
            uint32_t* d1 = eb + 256 + (q * 16 + col) * 4;    // b1 plane
            #pragma unroll
            for (int j = 0; j < 4; ++j) {
                d0[j] = pack2bf(row[q * 8 + 2 * j],      row[q * 8 + 2 * j + 1]);
                d1[j] = pack2bf(row[32 + q * 8 + 2 * j], row[32 + q * 8 + 2 * j + 1]);
            }
        }
    }
    float m = C;
    #pragma unroll
    for (int off = 32; off > 0; off >>= 1) m = fmaxf(m, __shfl_down(m, off, 64));
    if ((threadIdx.x & 63) == 0) smax[threadIdx.x >> 6] = m;
    __syncthreads();
    if (threadIdx.x == 0)
        ws[WS_MAXC + blockIdx.x] =
            fmaxf(fmaxf(smax[0], smax[1]), fmaxf(smax[2], smax[3]));
}

__global__ __launch_bounds__(256, 4) void vq_main(
        const float* __restrict__ inp, const float* __restrict__ emb,
        float* __restrict__ ws, float* __restrict__ out)
{
    __shared__ float    sA[PPB];
    __shared__ float    sPart[4][PPB];
    __shared__ float    sThr[PPB];
    __shared__ uint16_t sCand[PPB * 4 * 8];
    __shared__ uint8_t  sCnt[PPB * 4];
    __shared__ int      sWin[PPB];
    __shared__ float    sred[4];

    const int tid  = threadIdx.x;
    const int lane = tid & 63;
    const int wave = tid >> 6;          // = code quarter
    const int col  = lane & 15;
    const int quad = lane >> 4;
    const int base = blockIdx.x * PPB;
    const int b    = base >> 10;
    const int hw0  = base & 1023;

    // ---- prologue: exact A per point (wave 0) ------------------------------
    if (tid < PPB) {
        const float* xin = inp + (size_t)b * DDIM * HW + (hw0 + tid);
        float x[DDIM];
        #pragma unroll
        for (int d = 0; d < DDIM; ++d) x[d] = xin[(size_t)d * HW];
        sA[tid] = np_pairwise_sumsq64(x);
    }

    // ---- A-fragments for 4 row-groups (r8/r11-verified layout) -------------
    short8v a[4][2];
    #pragma unroll
    for (int g = 0; g < 4; ++g) {
        const float* xp = inp + (size_t)b * DDIM * HW + (hw0 + g * 16 + col);
        short8v t0, t1;
        #pragma unroll
        for (int j = 0; j < 8; ++j) {
            t0[j] = (short)f2bf(xp[(size_t)(quad * 8 + j) * HW]);
            t1[j] = (short)f2bf(xp[(size_t)(32 + quad * 8 + j) * HW]);
        }
        a[g][0] = t0; a[g][1] = t1;
    }

    // swizzled E: wave's chunks are [wave*16, wave*16+16); lane reads its own
    // 16B at chunk*2048 + plane*1024 + lane*16 — contiguous 1KB per wave-load.
    const char* Eb = (const char*)((const uint32_t*)ws + WS_E);
    const char* Ew = Eb + (size_t)wave * 16 * 2048 + (size_t)lane * 16;
    const float* Cw = ws + WS_C;
    const int k0 = wave * 256;

    // ---- sweep 1: per-point score-max, depth-2 pipelined loads -------------
    float smaxv[4][4];
    #pragma unroll
    for (int g = 0; g < 4; ++g)
        #pragma unroll
        for (int r = 0; r < 4; ++r) smaxv[g][r] = -3.0e38f;

    {
        short8v pa0 = *(const short8v*)(Ew);
        short8v pa1 = *(const short8v*)(Ew + 1024);
        short8v pb0 = *(const short8v*)(Ew + 2048);
        short8v pb1 = *(const short8v*)(Ew + 2048 + 1024);
        float   cia = Cw[k0 + col] * -0.5f;
        float   cib = Cw[k0 + 16 + col] * -0.5f;
        #pragma unroll 1
        for (int c2 = 0; c2 < 16; c2 += 2) {
            short8v u0 = pa0, u1 = pa1; float uci = cia;
            if (c2 + 2 < 16) {
                const char* er = Ew + (size_t)(c2 + 2) * 2048;
                pa0 = *(const short8v*)(er);
                pa1 = *(const short8v*)(er + 1024);
                cia = Cw[k0 + (c2 + 2) * 16 + col] * -0.5f;
            }
            float4v ci4 = {uci, uci, uci, uci};
            #pragma unroll
            for (int g = 0; g < 4; ++g) {
                float4v acc = ci4;
                acc = __builtin_amdgcn_mfma_f32_16x16x32_bf16(a[g][0], u0, acc, 0, 0, 0);
                acc = __builtin_amdgcn_mfma_f32_16x16x32_bf16(a[g][1], u1, acc, 0, 0, 0);
                #pragma unroll
                for (int r = 0; r < 4; ++r) smaxv[g][r] = fmaxf(smaxv[g][r], acc[r]);
            }
            short8v v0 = pb0, v1 = pb1; float vci = cib;
            if (c2 + 3 < 16) {
                const char* er = Ew + (size_t)(c2 + 3) * 2048;
                pb0 = *(const short8v*)(er);
                pb1 = *(const short8v*)(er + 1024);
                cib = Cw[k0 + (c2 + 3) * 16 + col] * -0.5f;
            }
            float4v ci4b = {vci, vci, vci, vci};
            #pragma unroll
            for (int g = 0; g < 4; ++g) {
                float4v acc = ci4b;
                acc = __builtin_amdgcn_mfma_f32_16x16x32_bf16(a[g][0], v0, acc, 0, 0, 0);
                acc = __builtin_amdgcn_mfma_f32_16x16x32_bf16(a[g][1], v1, acc, 0, 0, 0);
                #pragma unroll
                for (int r = 0; r < 4; ++r) smaxv[g][r] = fmaxf(smaxv[g][r], acc[r]);
            }
        }
    }
    #pragma unroll
    for (int g = 0; g < 4; ++g)
        #pragma unroll
        for (int r = 0; r < 4; ++r) {
            float m = smaxv[g][r];
            m = fmaxf(m, __shfl_xor(m, 1, 16));
            m = fmaxf(m, __shfl_xor(m, 2, 16));
            m = fmaxf(m, __shfl_xor(m, 4, 16));
            m = fmaxf(m, __shfl_xor(m, 8, 16));
            if (col == 0) sPart[wave][g * 16 + quad * 4 + r] = m;
        }
    __syncthreads();

    // ---- per-point threshold ------------------------------------------------
    if (tid < PPB) {
        float gm = fmaxf(fmaxf(sPart[0][tid], sPart[1][tid]),
                         fmaxf(sPart[2][tid], sPart[3][tid]));
        float mc = fmaxf(fmaxf(ws[WS_MAXC], ws[WS_MAXC + 1]),
                         fmaxf(ws[WS_MAXC + 2], ws[WS_MAXC + 3]));
        sThr[tid] = gm - (0.015625f * sqrtf(sA[tid]) * sqrtf(mc) + 6e-5f);
    }
    __syncthreads();

    float thr[4][4];
    #pragma unroll
    for (int g = 0; g < 4; ++g)
        #pragma unroll
        for (int r = 0; r < 4; ++r) thr[g][r] = sThr[g * 16 + quad * 4 + r];

    // ---- sweep 2: candidates (identical MFMA, depth-2 pipeline, ballot) ----
    int cnt[4][4];
    #pragma unroll
    for (int g = 0; g < 4; ++g)
        #pragma unroll
        for (int r = 0; r < 4; ++r) cnt[g][r] = 0;

    {
        short8v pa0 = *(const short8v*)(Ew);
        short8v pa1 = *(const short8v*)(Ew + 1024);
        short8v pb0 = *(const short8v*)(Ew + 2048);
        short8v pb1 = *(const short8v*)(Ew + 2048 + 1024);
        float   cia = Cw[k0 + col] * -0.5f;
        float   cib = Cw[k0 + 16 + col] * -0.5f;
        #pragma unroll 1
        for (int c2 = 0; c2 < 16; c2 += 2) {
            short8v u0 = pa0, u1 = pa1; float uci = cia;
            if (c2 + 2 < 16) {
                const char* er = Ew + (size_t)(c2 + 2) * 2048;
                pa0 = *(const short8v*)(er);
                pa1 = *(const short8v*)(er + 1024);
                cia = Cw[k0 + (c2 + 2) * 16 + col] * -0.5f;
            }
            float4v ci4 = {uci, uci, uci, uci};
            #pragma unroll
            for (int g = 0; g < 4; ++g) {
                float4v acc = ci4;
                acc = __builtin_amdgcn_mfma_f32_16x16x32_bf16(a[g][0], u0, acc, 0, 0, 0);
                acc = __builtin_amdgcn_mfma_f32_16x16x32_bf16(a[g][1], u1, acc, 0, 0, 0);
                #pragma unroll
                for (int r = 0; r < 4; ++r) {
                    unsigned long long bm = __ballot(acc[r] >= thr[g][r]);
                    if (col == 0) {
                        unsigned gm = (unsigned)(bm >> (quad * 16)) & 0xffffu;
                        while (gm) {
                            int bit = __ffs(gm) - 1;
                            gm &= gm - 1;
                            int ct = cnt[g][r];
                            if (ct < 8)
                                sCand[((g * 16 + quad * 4 + r) * 4 + wave) * 8 + ct] =
                                    (uint16_t)(k0 + c2 * 16 + bit);
                            cnt[g][r] = ct + 1;
                        }
                    }
                }
            }
            short8v v0 = pb0, v1 = pb1; float vci = cib;
            if (c2 + 3 < 16) {
                const char* er = Ew + (size_t)(c2 + 3) * 2048;
                pb0 = *(const short8v*)(er);
                pb1 = *(const short8v*)(er + 1024);
                cib = Cw[k0 + (c2 + 3) * 16 + col] * -0.5f;
            }
            float4v ci4b = {vci, vci, vci, vci};
            #pragma unroll
            for (int g = 0; g < 4; ++g) {
                float4v acc = ci4b;
                acc = __builtin_amdgcn_mfma_f32_16x16x32_bf16(a[g][0], v0, acc, 0, 0, 0);
                acc = __builtin_amdgcn_mfma_f32_16x16x32_bf16(a[g][1], v1, acc, 0, 0, 0);
                #pragma unroll
                for (int r = 0; r < 4; ++r) {
                    unsigned long long bm = __ballot(acc[r] >= thr[g][r]);
                    if (col == 0) {
                        unsigned gm = (unsigned)(bm >> (quad * 16)) & 0xffffu;
                        while (gm) {
                            int bit = __ffs(gm) - 1;
                            gm &= gm - 1;
                            int ct = cnt[g][r];
                            if (ct < 8)
                                sCand[((g * 16 + quad * 4 + r) * 4 + wave) * 8 + ct] =
                                    (uint16_t)(k0 + (c2 + 1) * 16 + bit);
                            cnt[g][r] = ct + 1;
                        }
                    }
                }
            }
        }
    }
    if (col == 0) {
        #pragma unroll
        for (int g = 0; g < 4; ++g)
            #pragma unroll
            for (int r = 0; r < 4; ++r) {
                int c = cnt[g][r];
                sCnt[(g * 16 + quad * 4 + r) * 4 + wave] = (uint8_t)(c > 255 ? 255 : c);
            }
    }
    __syncthreads();

    // ---- rescue: exact np-fp32 on candidates -------------------------------
    if (tid < PPB) {
        const int p = tid, n = base + p;
        int cq[4], tot = 0, cmax = 0;
        #pragma unroll
        for (int q = 0; q < 4; ++q) {
            cq[q] = sCnt[p * 4 + q];
            tot += cq[q];
            cmax = cq[q] > cmax ? cq[q] : cmax;
        }
        int win;
        if (tot == 1) {
            win = 0;
            #pragma unroll
            for (int q = 0; q < 4; ++q)
                if (cq[q]) win = sCand[(p * 4 + q) * 8];
        } else {
            const float* xin = inp + (size_t)b * DDIM * HW + (hw0 + p);
            float x[DDIM];
            #pragma unroll
            for (int d = 0; d < DDIM; ++d) x[d] = xin[(size_t)d * HW];
            const float A = sA[p];
            float bd = 3.0e38f; win = KCODES - 1;
            if (cmax <= 8) {
                #pragma unroll 1
                for (int q = 0; q < 4; ++q) {
                    #pragma unroll 1
                    for (int i = 0; i < cq[q]; ++i) {   // ascending k order
                        int k = sCand[(p * 4 + q) * 8 + i];
                        float e[DDIM];
                        const float4* e4 = (const float4*)(emb + (size_t)k * DDIM);
                        #pragma unroll
                        for (int j = 0; j < 16; ++j) ((float4*)e)[j] = e4[j];
                        float g = 0.f;
                        #pragma unroll
                        for (int d = 0; d < DDIM; ++d) g = fmaf(x[d], e[d], g);
                        float dd = __fadd_rn(__fsub_rn(A, __fmul_rn(2.0f, g)), Cw[k]);
                        if (dd < bd || (dd == bd && k < win)) { bd = dd; win = k; }
                    }
                }
            } else {                                    // overflow safety
                #pragma unroll 1
                for (int k = 0; k < KCODES; ++k) {
                    float e[DDIM];
                    const float4* e4 = (const float4*)(emb + (size_t)k * DDIM);
                    #pragma unroll
                    for (int j = 0; j < 16; ++j) ((float4*)e)[j] = e4[j];
                    float g = 0.f;
                    #pragma unroll
                    for (int d = 0; d < DDIM; ++d) g = fmaf(x[d], e[d], g);
                    float dd = __fadd_rn(__fsub_rn(A, __fmul_rn(2.0f, g)), Cw[k]);
                    if (dd < bd) { bd = dd; win = k; }
                }
            }
        }
        sWin[p] = win;
        out[OUT_IDX + n] = (float)win;
    }
    __syncthreads();

    // ---- epilogue: quantized NCHW + loss partial (plain store) -------------
    {
        const int pl = tid & 63, qtr = tid >> 6;
        const int win = sWin[pl];
        const int ch0 = qtr * 16;
        float q[16];
        const float4* q4 = (const float4*)(emb + (size_t)win * DDIM + ch0);
        #pragma unroll
        for (int j = 0; j < 4; ++j) ((float4*)q)[j] = q4[j];
        const size_t off = (size_t)b * DDIM * HW + (size_t)ch0 * HW + (hw0 + pl);
        const float* xin2 = inp + off;
        float* orow = out + off;
        float lacc = 0.f;
        #pragma unroll
        for (int j = 0; j < 16; ++j) {
            float xv = xin2[(size_t)j * HW];
            float diff = __fsub_rn(q[j], xv);
            orow[(size_t)j * HW] = __fadd_rn(xv, diff);   // ref's x + (q - x)
            lacc = fmaf(diff, diff, lacc);
        }
        #pragma unroll
        for (int o2 = 32; o2 > 0; o2 >>= 1) lacc += __shfl_down(lacc, o2, 64);
        if (lane == 0) sred[wave] = lacc;
    }
    __syncthreads();
    if (tid == 0)
        ws[WS_PART + blockIdx.x] = sred[0] + sred[1] + sred[2] + sred[3];
}

// 1 block x 256: reduce 1024 partials -> loss; write nll
__global__ __launch_bounds__(256) void vq_fin(const float* __restrict__ ws,
                                              float* __restrict__ out) {
    __shared__ float sred[4];
    const int tid = threadIdx.x;
    float s = 0.f;
    #pragma unroll
    for (int j = 0; j < 4; ++j) s += ws[WS_PART + j * 256 + tid];
    #pragma unroll
    for (int off = 32; off > 0; off >>= 1) s += __shfl_down(s, off, 64);
    if ((tid & 63) == 0) sred[tid >> 6] = s;
    __syncthreads();
    if (tid == 0) {
        float L = sred[0] + sred[1] + sred[2] + sred[3];
        out[OUT_LOSS] = L * (1.25f / 4194304.0f);   // (1+CC)*mean over N*D
        out[OUT_NLL]  = 1.0f;
    }
}

extern "C" void kernel_launch(void* const* d_in, const int* in_sizes, int n_in,
                              void* d_out, int out_size, void* d_ws, size_t ws_size,
                              hipStream_t stream) {
    const float* inp = (const float*)d_in[0];
    const float* emb = (const float*)d_in[1];
    float* out = (float*)d_out;
    float* ws  = (float*)d_ws;

    vq_init<<<4, 256, 0, stream>>>(emb, ws);
    vq_main<<<NBLK, 256, 0, stream>>>(inp, emb, ws, out);
    vq_fin<<<1, 256, 0, stream>>>(ws, out);
}

// Round 18
// 117.361 us; speedup vs baseline: 1.1264x; 1.0160x over previous
//
#include <hip/hip_runtime.h>
#include <stdint.h>

// VQ-VAE vector quantizer — fp32, NCHW input [64,64,32,32], emb [1024,64].
// r17 kernel (swizzled-E contiguous 1KB B-loads; main 55us; absmax 0.0
// twelve rounds) + parallelized exact-A prologue: numpy's pairwise tree
// ((r0+r1)+(r2+r3))+((r4+r5)+(r6+r7)) splits bit-exactly into 4 partials
// (thread t: point t>>2, r-pair (t&3)) combined in the threshold phase.
// 4x fewer prologue load instructions + segments; wave 0 off critical path.
constexpr int KCODES = 1024;
constexpr int DDIM   = 64;
constexpr int HW     = 1024;
constexpr int NPTS   = 65536;
constexpr int PPB    = 64;            // points per block
constexpr int NBLK   = NPTS / PPB;    // 1024

constexpr int OUT_Q    = 0;
constexpr int OUT_IDX  = 4194304;
constexpr int OUT_LOSS = 4259840;
constexpr int OUT_NLL  = 4259841;

// ws 32-bit-unit offsets
constexpr int WS_MAXC  = 0;       // 4 f   : per-init-block max C
constexpr int WS_C     = 16;      // 1024 f: exact np C_k
constexpr int WS_E     = 2048;    // 32768 u32: SWIZZLED bf16-E (64 chunks x 2KB)
constexpr int WS_PART  = 34816;   // 1024 f: per-block loss partials

typedef __attribute__((ext_vector_type(8))) short short8v;
typedef __attribute__((ext_vector_type(4))) float float4v;

__device__ __forceinline__ uint16_t f2bf(float f) {   // RNE fp32->bf16
    uint32_t u = __float_as_uint(f);
    return (uint16_t)((u + 0x7fffu + ((u >> 16) & 1u)) >> 16);
}
__device__ __forceinline__ uint32_t pack2bf(float a, float b) {
    return (uint32_t)f2bf(a) | ((uint32_t)f2bf(b) << 16);
}

__device__ __forceinline__ float np_pairwise_sumsq64(const float* a) {
    float r[8];
    #pragma unroll
    for (int j = 0; j < 8; ++j) r[j] = __fmul_rn(a[j], a[j]);
    #pragma unroll
    for (int i = 8; i < 64; i += 8)
        #pragma unroll
        for (int j = 0; j < 8; ++j)
            r[j] = __fadd_rn(r[j], __fmul_rn(a[i + j], a[i + j]));
    return __fadd_rn(__fadd_rn(__fadd_rn(r[0], r[1]), __fadd_rn(r[2], r[3])),
                     __fadd_rn(__fadd_rn(r[4], r[5]), __fadd_rn(r[6], r[7])));
}

// 4 blocks x 256 threads: code k = blockIdx*256 + tid. Writes SWIZZLED E.
__global__ __launch_bounds__(256) void vq_init(const float* __restrict__ emb,
                                               float* __restrict__ ws) {
    __shared__ float smax[4];
    const int k = blockIdx.x * 256 + threadIdx.x;
    float row[DDIM];
    const float4* src = (const float4*)(emb + (size_t)k * DDIM);
    #pragma unroll
    for (int j = 0; j < 16; ++j) ((float4*)row)[j] = src[j];
    float C = np_pairwise_sumsq64(row);
    ws[WS_C + k] = C;
    {
        const int c = k >> 4, col = k & 15;
        uint32_t* eb = (uint32_t*)ws + WS_E + c * 512;   // chunk base (u32)
        #pragma unroll
        for (int q = 0; q < 4; ++q) {
            uint32_t* d0 = eb + (q * 16 + col) * 4;          // b0 plane
            uint32_t* d1 = eb + 256 + (q * 16 + col) * 4;    // b1 plane
            #pragma unroll
            for (int j = 0; j < 4; ++j) {
                d0[j] = pack2bf(row[q * 8 + 2 * j],      row[q * 8 + 2 * j + 1]);
                d1[j] = pack2bf(row[32 + q * 8 + 2 * j], row[32 + q * 8 + 2 * j + 1]);
            }
        }
    }
    float m = C;
    #pragma unroll
    for (int off = 32; off > 0; off >>= 1) m = fmaxf(m, __shfl_down(m, off, 64));
    if ((threadIdx.x & 63) == 0) smax[threadIdx.x >> 6] = m;
    __syncthreads();
    if (threadIdx.x == 0)
        ws[WS_MAXC + blockIdx.x] =
            fmaxf(fmaxf(smax[0], smax[1]), fmaxf(smax[2], smax[3]));
}

__global__ __launch_bounds__(256, 4) void vq_main(
        const float* __restrict__ inp, const float* __restrict__ emb,
        float* __restrict__ ws, float* __restrict__ out)
{
    __shared__ float    sAp[PPB][4];    // pairwise partials (r2j + r2j+1)
    __shared__ float    sA[PPB];
    __shared__ float    sPart[4][PPB];
    __shared__ float    sThr[PPB];
    __shared__ uint16_t sCand[PPB * 4 * 8];
    __shared__ uint8_t  sCnt[PPB * 4];
    __shared__ int      sWin[PPB];
    __shared__ float    sred[4];

    const int tid  = threadIdx.x;
    const int lane = tid & 63;
    const int wave = tid >> 6;          // = code quarter
    const int col  = lane & 15;
    const int quad = lane >> 4;
    const int base = blockIdx.x * PPB;
    const int b    = base >> 10;
    const int hw0  = base & 1023;

    // ---- prologue: exact-A partials, 4 threads per point (bit-exact tree
    //      split of np pairwise: this thread computes r_{2j}+r_{2j+1}) -------
    {
        const int pp = tid >> 2;            // point
        const int jj = (tid & 3) * 2;       // r-pair base
        const float* xin = inp + (size_t)b * DDIM * HW + (hw0 + pp);
        float r0, r1;
        {
            float v0 = xin[(size_t)jj * HW];
            float v1 = xin[(size_t)(jj + 1) * HW];
            r0 = __fmul_rn(v0, v0);
            r1 = __fmul_rn(v1, v1);
        }
        #pragma unroll
        for (int i = 8; i < 64; i += 8) {
            float v0 = xin[(size_t)(i + jj) * HW];
            float v1 = xin[(size_t)(i + jj + 1) * HW];
            r0 = __fadd_rn(r0, __fmul_rn(v0, v0));
            r1 = __fadd_rn(r1, __fmul_rn(v1, v1));
        }
        sAp[pp][tid & 3] = __fadd_rn(r0, r1);
    }

    // ---- A-fragments for 4 row-groups (r8/r11-verified layout) -------------
    short8v a[4][2];
    #pragma unroll
    for (int g = 0; g < 4; ++g) {
        const float* xp = inp + (size_t)b * DDIM * HW + (hw0 + g * 16 + col);
        short8v t0, t1;
        #pragma unroll
        for (int j = 0; j < 8; ++j) {
            t0[j] = (short)f2bf(xp[(size_t)(quad * 8 + j) * HW]);
            t1[j] = (short)f2bf(xp[(size_t)(32 + quad * 8 + j) * HW]);
        }
        a[g][0] = t0; a[g][1] = t1;
    }

    // swizzled E: lane reads its 16B at chunk*2048 + plane*1024 + lane*16 —
    // contiguous 1KB per wave-load (r17-proven 15% win).
    const char* Eb = (const char*)((const uint32_t*)ws + WS_E);
    const char* Ew = Eb + (size_t)wave * 16 * 2048 + (size_t)lane * 16;
    const float* Cw = ws + WS_C;
    const int k0 = wave * 256;

    // ---- sweep 1: per-point score-max, depth-2 pipelined loads -------------
    float smaxv[4][4];
    #pragma unroll
    for (int g = 0; g < 4; ++g)
        #pragma unroll
        for (int r = 0; r < 4; ++r) smaxv[g][r] = -3.0e38f;

    {
        short8v pa0 = *(const short8v*)(Ew);
        short8v pa1 = *(const short8v*)(Ew + 1024);
        short8v pb0 = *(const short8v*)(Ew + 2048);
        short8v pb1 = *(const short8v*)(Ew + 2048 + 1024);
        float   cia = Cw[k0 + col] * -0.5f;
        float   cib = Cw[k0 + 16 + col] * -0.5f;
        #pragma unroll 1
        for (int c2 = 0; c2 < 16; c2 += 2) {
            short8v u0 = pa0, u1 = pa1; float uci = cia;
            if (c2 + 2 < 16) {
                const char* er = Ew + (size_t)(c2 + 2) * 2048;
                pa0 = *(const short8v*)(er);
                pa1 = *(const short8v*)(er + 1024);
                cia = Cw[k0 + (c2 + 2) * 16 + col] * -0.5f;
            }
            float4v ci4 = {uci, uci, uci, uci};
            #pragma unroll
            for (int g = 0; g < 4; ++g) {
                float4v acc = ci4;
                acc = __builtin_amdgcn_mfma_f32_16x16x32_bf16(a[g][0], u0, acc, 0, 0, 0);
                acc = __builtin_amdgcn_mfma_f32_16x16x32_bf16(a[g][1], u1, acc, 0, 0, 0);
                #pragma unroll
                for (int r = 0; r < 4; ++r) smaxv[g][r] = fmaxf(smaxv[g][r], acc[r]);
            }
            short8v v0 = pb0, v1 = pb1; float vci = cib;
            if (c2 + 3 < 16) {
                const char* er = Ew + (size_t)(c2 + 3) * 2048;
                pb0 = *(const short8v*)(er);
                pb1 = *(const short8v*)(er + 1024);
                cib = Cw[k0 + (c2 + 3) * 16 + col] * -0.5f;
            }
            float4v ci4b = {vci, vci, vci, vci};
            #pragma unroll
            for (int g = 0; g < 4; ++g) {
                float4v acc = ci4b;
                acc = __builtin_amdgcn_mfma_f32_16x16x32_bf16(a[g][0], v0, acc, 0, 0, 0);
                acc = __builtin_amdgcn_mfma_f32_16x16x32_bf16(a[g][1], v1, acc, 0, 0, 0);
                #pragma unroll
                for (int r = 0; r < 4; ++r) smaxv[g][r] = fmaxf(smaxv[g][r], acc[r]);
            }
        }
    }
    #pragma unroll
    for (int g = 0; g < 4; ++g)
        #pragma unroll
        for (int r = 0; r < 4; ++r) {
            float m = smaxv[g][r];
            m = fmaxf(m, __shfl_xor(m, 1, 16));
            m = fmaxf(m, __shfl_xor(m, 2, 16));
            m = fmaxf(m, __shfl_xor(m, 4, 16));
            m = fmaxf(m, __shfl_xor(m, 8, 16));
            if (col == 0) sPart[wave][g * 16 + quad * 4 + r] = m;
        }
    __syncthreads();

    // ---- per-point threshold (also combine exact-A partials, exact tree) ---
    if (tid < PPB) {
        float A = __fadd_rn(__fadd_rn(sAp[tid][0], sAp[tid][1]),
                            __fadd_rn(sAp[tid][2], sAp[tid][3]));
        sA[tid] = A;
        float gm = fmaxf(fmaxf(sPart[0][tid], sPart[1][tid]),
                         fmaxf(sPart[2][tid], sPart[3][tid]));
        float mc = fmaxf(fmaxf(ws[WS_MAXC], ws[WS_MAXC + 1]),
                         fmaxf(ws[WS_MAXC + 2], ws[WS_MAXC + 3]));
        sThr[tid] = gm - (0.015625f * sqrtf(A) * sqrtf(mc) + 6e-5f);
    }
    __syncthreads();

    float thr[4][4];
    #pragma unroll
    for (int g = 0; g < 4; ++g)
        #pragma unroll
        for (int r = 0; r < 4; ++r) thr[g][r] = sThr[g * 16 + quad * 4 + r];

    // ---- sweep 2: candidates (identical MFMA, depth-2 pipeline, ballot) ----
    int cnt[4][4];
    #pragma unroll
    for (int g = 0; g < 4; ++g)
        #pragma unroll
        for (int r = 0; r < 4; ++r) cnt[g][r] = 0;

    {
        short8v pa0 = *(const short8v*)(Ew);
        short8v pa1 = *(const short8v*)(Ew + 1024);
        short8v pb0 = *(const short8v*)(Ew + 2048);
        short8v pb1 = *(const short8v*)(Ew + 2048 + 1024);
        float   cia = Cw[k0 + col] * -0.5f;
        float   cib = Cw[k0 + 16 + col] * -0.5f;
        #pragma unroll 1
        for (int c2 = 0; c2 < 16; c2 += 2) {
            short8v u0 = pa0, u1 = pa1; float uci = cia;
            if (c2 + 2 < 16) {
                const char* er = Ew + (size_t)(c2 + 2) * 2048;
                pa0 = *(const short8v*)(er);
                pa1 = *(const short8v*)(er + 1024);
                cia = Cw[k0 + (c2 + 2) * 16 + col] * -0.5f;
            }
            float4v ci4 = {uci, uci, uci, uci};
            #pragma unroll
            for (int g = 0; g < 4; ++g) {
                float4v acc = ci4;
                acc = __builtin_amdgcn_mfma_f32_16x16x32_bf16(a[g][0], u0, acc, 0, 0, 0);
                acc = __builtin_amdgcn_mfma_f32_16x16x32_bf16(a[g][1], u1, acc, 0, 0, 0);
                #pragma unroll
                for (int r = 0; r < 4; ++r) {
                    unsigned long long bm = __ballot(acc[r] >= thr[g][r]);
                    if (col == 0) {
                        unsigned gm = (unsigned)(bm >> (quad * 16)) & 0xffffu;
                        while (gm) {
                            int bit = __ffs(gm) - 1;
                            gm &= gm - 1;
                            int ct = cnt[g][r];
                            if (ct < 8)
                                sCand[((g * 16 + quad * 4 + r) * 4 + wave) * 8 + ct] =
                                    (uint16_t)(k0 + c2 * 16 + bit);
                            cnt[g][r] = ct + 1;
                        }
                    }
                }
            }
            short8v v0 = pb0, v1 = pb1; float vci = cib;
            if (c2 + 3 < 16) {
                const char* er = Ew + (size_t)(c2 + 3) * 2048;
                pb0 = *(const short8v*)(er);
                pb1 = *(const short8v*)(er + 1024);
                cib = Cw[k0 + (c2 + 3) * 16 + col] * -0.5f;
            }
            float4v ci4b = {vci, vci, vci, vci};
            #pragma unroll
            for (int g = 0; g < 4; ++g) {
                float4v acc = ci4b;
                acc = __builtin_amdgcn_mfma_f32_16x16x32_bf16(a[g][0], v0, acc, 0, 0, 0);
                acc = __builtin_amdgcn_mfma_f32_16x16x32_bf16(a[g][1], v1, acc, 0, 0, 0);
                #pragma unroll
                for (int r = 0; r < 4; ++r) {
                    unsigned long long bm = __ballot(acc[r] >= thr[g][r]);
                    if (col == 0) {
                        unsigned gm = (unsigned)(bm >> (quad * 16)) & 0xffffu;
                        while (gm) {
                            int bit = __ffs(gm) - 1;
                            gm &= gm - 1;
                            int ct = cnt[g][r];
                            if (ct < 8)
                                sCand[((g * 16 + quad * 4 + r) * 4 + wave) * 8 + ct] =
                                    (uint16_t)(k0 + (c2 + 1) * 16 + bit);
                            cnt[g][r] = ct + 1;
                        }
                    }
                }
            }
        }
    }
    if (col == 0) {
        #pragma unroll
        for (int g = 0; g < 4; ++g)
            #pragma unroll
            for (int r = 0; r < 4; ++r) {
                int c = cnt[g][r];
                sCnt[(g * 16 + quad * 4 + r) * 4 + wave] = (uint8_t)(c > 255 ? 255 : c);
            }
    }
    __syncthreads();

    // ---- rescue: exact np-fp32 on candidates -------------------------------
    if (tid < PPB) {
        const int p = tid, n = base + p;
        int cq[4], tot = 0, cmax = 0;
        #pragma unroll
        for (int q = 0; q < 4; ++q) {
            cq[q] = sCnt[p * 4 + q];
            tot += cq[q];
            cmax = cq[q] > cmax ? cq[q] : cmax;
        }
        int win;
        if (tot == 1) {
            win = 0;
            #pragma unroll
            for (int q = 0; q < 4; ++q)
                if (cq[q]) win = sCand[(p * 4 + q) * 8];
        } else {
            const float* xin = inp + (size_t)b * DDIM * HW + (hw0 + p);
            float x[DDIM];
            #pragma unroll
            for (int d = 0; d < DDIM; ++d) x[d] = xin[(size_t)d * HW];
            const float A = sA[p];
            float bd = 3.0e38f; win = KCODES - 1;
            if (cmax <= 8) {
                #pragma unroll 1
                for (int q = 0; q < 4; ++q) {
                    #pragma unroll 1
                    for (int i = 0; i < cq[q]; ++i) {   // ascending k order
                        int k = sCand[(p * 4 + q) * 8 + i];
                        float e[DDIM];
                        const float4* e4 = (const float4*)(emb + (size_t)k * DDIM);
                        #pragma unroll
                        for (int j = 0; j < 16; ++j) ((float4*)e)[j] = e4[j];
                        float g = 0.f;
                        #pragma unroll
                        for (int d = 0; d < DDIM; ++d) g = fmaf(x[d], e[d], g);
                        float dd = __fadd_rn(__fsub_rn(A, __fmul_rn(2.0f, g)), Cw[k]);
                        if (dd < bd || (dd == bd && k < win)) { bd = dd; win = k; }
                    }
                }
            } else {                                    // overflow safety
                #pragma unroll 1
                for (int k = 0; k < KCODES; ++k) {
                    float e[DDIM];
                    const float4* e4 = (const float4*)(emb + (size_t)k * DDIM);
                    #pragma unroll
                    for (int j = 0; j < 16; ++j) ((float4*)e)[j] = e4[j];
                    float g = 0.f;
                    #pragma unroll
                    for (int d = 0; d < DDIM; ++d) g = fmaf(x[d], e[d], g);
                    float dd = __fadd_rn(__fsub_rn(A, __fmul_rn(2.0f, g)), Cw[k]);
                    if (dd < bd) { bd = dd; win = k; }
                }
            }
        }
        sWin[p] = win;
        out[OUT_IDX + n] = (float)win;
    }
    __syncthreads();

    // ---- epilogue: quantized NCHW + loss partial (plain store) -------------
    {
        const int pl = tid & 63, qtr = tid >> 6;
        const int win = sWin[pl];
        const int ch0 = qtr * 16;
        float q[16];
        const float4* q4 = (const float4*)(emb + (size_t)win * DDIM + ch0);
        #pragma unroll
        for (int j = 0; j < 4; ++j) ((float4*)q)[j] = q4[j];
        const size_t off = (size_t)b * DDIM * HW + (size_t)ch0 * HW + (hw0 + pl);
        const float* xin2 = inp + off;
        float* orow = out + off;
        float lacc = 0.f;
        #pragma unroll
        for (int j = 0; j < 16; ++j) {
            float xv = xin2[(size_t)j * HW];
            float diff = __fsub_rn(q[j], xv);
            orow[(size_t)j * HW] = __fadd_rn(xv, diff);   // ref's x + (q - x)
            lacc = fmaf(diff, diff, lacc);
        }
        #pragma unroll
        for (int o2 = 32; o2 > 0; o2 >>= 1) lacc += __shfl_down(lacc, o2, 64);
        if (lane == 0) sred[wave] = lacc;
    }
    __syncthreads();
    if (tid == 0)
        ws[WS_PART + blockIdx.x] = sred[0] + sred[1] + sred[2] + sred[3];
}

// 1 block x 256: reduce 1024 partials -> loss; write nll
__global__ __launch_bounds__(256) void vq_fin(const float* __restrict__ ws,
                                              float* __restrict__ out) {
    __shared__ float sred[4];
    const int tid = threadIdx.x;
    float s = 0.f;
    #pragma unroll
    for (int j = 0; j < 4; ++j) s += ws[WS_PART + j * 256 + tid];
    #pragma unroll
    for (int off = 32; off > 0; off >>= 1) s += __shfl_down(s, off, 64);
    if ((tid & 63) == 0) sred[tid >> 6] = s;
    __syncthreads();
    if (tid == 0) {
        float L = sred[0] + sred[1] + sred[2] + sred[3];
        out[OUT_LOSS] = L * (1.25f / 4194304.0f);   // (1+CC)*mean over N*D
        out[OUT_NLL]  = 1.0f;
    }
}

extern "C" void kernel_launch(void* const* d_in, const int* in_sizes, int n_in,
                              void* d_out, int out_size, void* d_ws, size_t ws_size,
                              hipStream_t stream) {
    const float* inp = (const float*)d_in[0];
    const float* emb = (const float*)d_in[1];
    float* out = (float*)d_out;
    float* ws  = (float*)d_ws;

    vq_init<<<4, 256, 0, stream>>>(emb, ws);
    vq_main<<<NBLK, 256, 0, stream>>>(inp, emb, ws, out);
    vq_fin<<<1, 256, 0, stream>>>(ws, out);
}